// Round 6
// baseline (291.614 us; speedup 1.0000x reference)
//
#include <hip/hip_runtime.h>
#include <stdint.h>

// ---------- sizes (fixed by setup_inputs) ----------
#define BATCH   65536
#define FIN     32        // layer-1 in
#define HID     64        // layer-1 out / layer-2 in
#define NOUT    2048      // layer-2 out
#define NC      8         // bases per element
#define NF      9         // features per element (silu + 8 bases)
#define K1      288       // FIN*NF
#define K2      576       // HID*NF

// ---------- GEMM2 tiling ----------
#define BM      256
#define BN      256
#define BK      32
#define KT      18        // K2/BK
#define NBUF    4

typedef __bf16 bf16x8 __attribute__((ext_vector_type(8)));
typedef float f32x4 __attribute__((ext_vector_type(4)));

// ---------- helpers ----------
__device__ __forceinline__ uint16_t f2bf(float f) {
    uint32_t u = __builtin_bit_cast(uint32_t, f);
    uint32_t r = (u + 0x7fffu + ((u >> 16) & 1u)) >> 16;
    return (uint16_t)r;
}
__device__ __forceinline__ float silu_f(float v) {
    return v / (1.f + __expf(-v));
}

// Closed-form uniform cubic B-spline bases. Knots g[t]=(t-3)*0.4-1, t=0..11.
__device__ __forceinline__ void bspline8u(float xv, float out[8]) {
    float s = (xv + 2.2f) * 2.5f;
    int c = (int)floorf(s);
    float gc = (float)(c - 3) * 0.4f - 1.0f;
    float u = (xv - gc) * 2.5f;
    float u1 = 1.f - u;
    float uu = u * u, u3 = uu * u;
    float w0 = u1 * u1 * u1 * (1.f / 6.f);
    float w1 = (3.f * u3 - 6.f * uu + 4.f) * (1.f / 6.f);
    float w2 = (-3.f * u3 + 3.f * uu + 3.f * u + 1.f) * (1.f / 6.f);
    float w3 = u3 * (1.f / 6.f);
#pragma unroll
    for (int t = 0; t < 8; t++) {
        int d = c - t;
        out[t] = (d == 0) ? w3 : (d == 1) ? w2 : (d == 2) ? w1 : (d == 3) ? w0 : 0.f;
    }
}

// ---------- pack kernels ----------
__global__ void pack_w1(const float* __restrict__ bw1, const float* __restrict__ sw1,
                        const float* __restrict__ ss1, uint16_t* __restrict__ w1L) {
    int idx = blockIdx.x * 256 + threadIdx.x;
    if (idx >= 64 * K1) return;
    int o = idx / K1, k = idx % K1;
    int i = k / 9, j = k % 9;
    float v = (j == 0) ? bw1[o * FIN + i]
                       : sw1[(o * FIN + i) * NC + (j - 1)] * ss1[o * FIN + i];
    w1L[idx] = f2bf(v);
}

__global__ void pack_w2(const float* __restrict__ bw2, const float* __restrict__ sw2,
                        const float* __restrict__ ss2, uint16_t* __restrict__ w2p) {
    int idx = blockIdx.x * 256 + threadIdx.x;
    if (idx >= NOUT * K2) return;
    int n = idx / K2, k = idx % K2;
    int j = k >> 6, i = k & 63;
    float v = (j == 0) ? bw2[n * HID + i]
                       : sw2[(n * HID + i) * NC + (j - 1)] * ss2[n * HID + i];
    w2p[idx] = f2bf(v);
}

// ---------- fused LN + featurize1 + MFMA layer1 + featurize2 ----------
// LDS plan: [0,37888) = W1 [64][296]; [37888,75776) = A1 [64][296].
// After the layer-1 MFMA both are dead -> reuse as A2 stage [64][584]
// (74752 B), flushed coalesced to global.
#define FBR    64
#define A1LD   296
#define S2LD   584
__global__ __launch_bounds__(256) void featurize(
    const float* __restrict__ x, const float* __restrict__ lnw, const float* __restrict__ lnb,
    const uint16_t* __restrict__ w1L, uint16_t* __restrict__ a2) {

    __shared__ __align__(16) char fsm[75776];
    uint16_t* w1s = (uint16_t*)fsm;              // [64][296]
    uint16_t* a1s = (uint16_t*)(fsm + 37888);    // [64][296]
    uint16_t* s2  = (uint16_t*)fsm;              // [64][584] (phase 3)

    const int tid = threadIdx.x;
    const int wv = tid >> 6, lane = tid & 63;
    const int rowBase = blockIdx.x * FBR;

    // ---- stage W1 [64][288] -> [64][296] ----
#pragma unroll
    for (int t = 0; t < 9; ++t) {
        int idx = t * 256 + tid;
        int o = idx / 36, cc = idx % 36;
        uint4 v = *(const uint4*)(w1L + idx * 8);
        *(uint4*)&w1s[o * A1LD + cc * 8] = v;
    }

    // ---- phase 1: LN + featurize x (4 threads/row, 8 inputs each) ----
    const int prow = tid >> 2, pq = tid & 3;
    const float* xp = x + (size_t)(rowBase + prow) * FIN + pq * 8;
    float xv[8];
    *(float4*)&xv[0] = ((const float4*)xp)[0];
    *(float4*)&xv[4] = ((const float4*)xp)[1];
    float s = 0.f, s2v = 0.f;
#pragma unroll
    for (int j = 0; j < 8; j++) { s += xv[j]; s2v += xv[j] * xv[j]; }
    s += __shfl_xor(s, 1);  s2v += __shfl_xor(s2v, 1);
    s += __shfl_xor(s, 2);  s2v += __shfl_xor(s2v, 2);
    const float mu = s * (1.f / 32.f);
    const float var = s2v * (1.f / 32.f) - mu * mu;
    const float rstd = rsqrtf(var + 1e-5f);

    float wl[8], bl[8];
    *(float4*)&wl[0] = ((const float4*)(lnw + pq * 8))[0];
    *(float4*)&wl[4] = ((const float4*)(lnw + pq * 8))[1];
    *(float4*)&bl[0] = ((const float4*)(lnb + pq * 8))[0];
    *(float4*)&bl[4] = ((const float4*)(lnb + pq * 8))[1];

    __align__(16) uint16_t tmp[72];
#pragma unroll
    for (int ii = 0; ii < 8; ii++) {
        float xn = (xv[ii] - mu) * rstd * wl[ii] + bl[ii];
        tmp[ii * 9] = f2bf(silu_f(xn));
        float bs[8];
        bspline8u(xn, bs);
#pragma unroll
        for (int j = 0; j < 8; j++) tmp[ii * 9 + 1 + j] = f2bf(bs[j]);
    }
    {
        uint16_t* dst = &a1s[prow * A1LD + pq * 72];
#pragma unroll
        for (int q = 0; q < 9; q++) *(uint4*)(dst + q * 8) = *(const uint4*)&tmp[q * 8];
    }
    __syncthreads();

    // ---- phase 2: h = A1 x W1 via MFMA; wave w owns rows w*16..w*16+15 ----
    f32x4 acc[4];
#pragma unroll
    for (int n = 0; n < 4; n++) acc[n] = (f32x4){0.f, 0.f, 0.f, 0.f};
    const int arow = wv * 16 + (lane & 15);
    const int koff = (lane >> 4) * 8;
#pragma unroll
    for (int ks = 0; ks < 9; ++ks) {
        bf16x8 af = *(const bf16x8*)&a1s[arow * A1LD + ks * 32 + koff];
#pragma unroll
        for (int n = 0; n < 4; n++) {
            bf16x8 bv = *(const bf16x8*)&w1s[(n * 16 + (lane & 15)) * A1LD + ks * 32 + koff];
            acc[n] = __builtin_amdgcn_mfma_f32_16x16x32_bf16(af, bv, acc[n], 0, 0, 0);
        }
    }
    __syncthreads();   // w1s/a1s dead; s2 aliases them

    // ---- phase 3: featurize h into LDS stage ----
    const int r0 = wv * 16 + ((lane >> 4) << 2);
    const int cb = lane & 15;
#pragma unroll
    for (int n = 0; n < 4; n++)
#pragma unroll
        for (int r = 0; r < 4; r++) {
            float h = acc[n][r];
            float o9[9];
            o9[0] = silu_f(h);
            bspline8u(h, &o9[1]);
            uint16_t* op = &s2[(size_t)(r0 + r) * S2LD + n * 16 + cb];
#pragma unroll
            for (int j = 0; j < 9; j++) op[j * 64] = f2bf(o9[j]);
        }
    __syncthreads();

    // ---- phase 4: coalesced flush LDS -> a2 ----
    // 64 rows x 576 cols = 4608 chunks of 8 bf16 (16 B); 18 iters x 256 thr.
    // (r5 BUG was /36,%36 with 9 iters: flushed only cols 0..287.)
#pragma unroll
    for (int q = 0; q < 18; ++q) {
        int g = q * 256 + tid;           // chunk id, row-major
        int row = g / 72, c = g % 72;
        uint4 v = *(const uint4*)&s2[row * S2LD + c * 8];
        *(uint4*)(a2 + (size_t)(rowBase + row) * K2 + c * 8) = v;
    }
}

// ---------- GEMM2: (65536 x 576) x (576 x 2048) ----------
// 256x256 tile, 8 waves (2M x 4N), BK=32, NBUF=4 ring, counted vmcnt.
// Fine-phase cadence (T3+T4): 4 phases/K-tile, each {ds_reads + 1 stage
// issue -> barrier -> lgkmcnt(0) -> sched_barrier -> setprio(1) -> 8 MFMA
// -> setprio(0) -> barrier}; vmcnt(8) once per tile (tail 4 -> 0).
__device__ __forceinline__ void gload16(const uint16_t* g, const uint16_t* l) {
    __builtin_amdgcn_global_load_lds(
        (const __attribute__((address_space(1))) void*)g,
        (__attribute__((address_space(3))) void*)l, 16, 0, 0);
}

__global__ __launch_bounds__(512, 2) void gemm2_kernel(const uint16_t* __restrict__ A,
                                                       const uint16_t* __restrict__ Bt,
                                                       float* __restrict__ C) {
    __shared__ __align__(16) uint16_t lds[NBUF][2][BM * BK];   // 128 KiB

    const int tid = threadIdx.x;
    const int wv = tid >> 6, lane = tid & 63;
    const int wr = wv >> 2, wc = wv & 3;          // 2 x 4 wave grid

    // XCD-aware bijective swizzle (2048 blocks, 2048 % 8 == 0)
    const uint32_t bid = blockIdx.x;
    const uint32_t wk = (bid & 7u) * 256u + (bid >> 3);
    const uint32_t ntile = wk & 7u, mtile = wk >> 3;

    // Linear LDS dest + pre-swizzled GLOBAL source column (rule 21).
    const int srow = tid >> 2;
    const int scol = (((tid & 3) ^ ((tid >> 3) & 3)) << 3);
    const uint16_t* gA = A  + (size_t)(mtile * BM + srow) * K2 + scol;
    const uint16_t* gB = Bt + (size_t)(ntile * BN + srow) * K2 + scol;

    // Fragment reads: slot' = (lane>>4) ^ ((row>>1)&3) -> b128 minimum.
    const int slot8 = (((lane >> 4) ^ ((lane >> 1) & 3)) << 3);
    const int aoff = (wr * 128 + (lane & 15)) * BK + slot8;
    const int boff = (wc * 64  + (lane & 15)) * BK + slot8;

    f32x4 acc[8][4];
#pragma unroll
    for (int m = 0; m < 8; m++)
#pragma unroll
        for (int n = 0; n < 4; n++) acc[m][n] = (f32x4){0.f, 0.f, 0.f, 0.f};

    // Staging lines (per wave, 1 instr each): A0,A1,B0,B1 of one K-tile.
#define ST_A0(b, kt) gload16(gA + (kt) * BK,                    &lds[b][0][wv * 512])
#define ST_A1(b, kt) gload16(gA + (size_t)128 * K2 + (kt) * BK, &lds[b][0][4096 + wv * 512])
#define ST_B0(b, kt) gload16(gB + (kt) * BK,                    &lds[b][1][wv * 512])
#define ST_B1(b, kt) gload16(gB + (size_t)128 * K2 + (kt) * BK, &lds[b][1][4096 + wv * 512])

    // Prologue: stage tiles 0,1,2 (12 issues); tile 0 resident after vmcnt(8).
    ST_A0(0, 0); ST_A1(0, 0); ST_B0(0, 0); ST_B1(0, 0);
    ST_A0(1, 1); ST_A1(1, 1); ST_B0(1, 1); ST_B1(1, 1);
    ST_A0(2, 2); ST_A1(2, 2); ST_B0(2, 2); ST_B1(2, 2);
    asm volatile("s_waitcnt vmcnt(8)" ::: "memory");
    asm volatile("s_barrier" ::: "memory");

#pragma unroll
    for (int t = 0; t < KT; ++t) {
        const int b = t & 3;
        const int nb = (t + 3) & 3;
        const bool st = (t + 3 < KT);
        const uint16_t* As = &lds[b][0][0];
        const uint16_t* Bs = &lds[b][1][0];
        bf16x8 bv[4], aa, ab;

        // ---- P1: B frags + A m0,m1; stage A-line0(t+3) ----
#pragma unroll
        for (int n = 0; n < 4; ++n) bv[n] = *(const bf16x8*)&Bs[boff + n * 512];
        aa = *(const bf16x8*)&As[aoff];
        ab = *(const bf16x8*)&As[aoff + 512];
        if (st) ST_A0(nb, t + 3);
        asm volatile("s_barrier" ::: "memory");
        asm volatile("s_waitcnt lgkmcnt(0)" ::: "memory");
        __builtin_amdgcn_sched_barrier(0);
        __builtin_amdgcn_s_setprio(1);
#pragma unroll
        for (int n = 0; n < 4; ++n) acc[0][n] = __builtin_amdgcn_mfma_f32_16x16x32_bf16(aa, bv[n], acc[0][n], 0, 0, 0);
#pragma unroll
        for (int n = 0; n < 4; ++n) acc[1][n] = __builtin_amdgcn_mfma_f32_16x16x32_bf16(ab, bv[n], acc[1][n], 0, 0, 0);
        __builtin_amdgcn_s_setprio(0);
        asm volatile("s_barrier" ::: "memory");

        // ---- P2: A m2,m3; stage A-line1(t+3) ----
        aa = *(const bf16x8*)&As[aoff + 2 * 512];
        ab = *(const bf16x8*)&As[aoff + 3 * 512];
        if (st) ST_A1(nb, t + 3);
        asm volatile("s_barrier" ::: "memory");
        asm volatile("s_waitcnt lgkmcnt(0)" ::: "memory");
        __builtin_amdgcn_sched_barrier(0);
        __builtin_amdgcn_s_setprio(1);
#pragma unroll
        for (int n = 0; n < 4; ++n) acc[2][n] = __builtin_amdgcn_mfma_f32_16x16x32_bf16(aa, bv[n], acc[2][n], 0, 0, 0);
#pragma unroll
        for (int n = 0; n < 4; ++n) acc[3][n] = __builtin_amdgcn_mfma_f32_16x16x32_bf16(ab, bv[n], acc[3][n], 0, 0, 0);
        __builtin_amdgcn_s_setprio(0);
        asm volatile("s_barrier" ::: "memory");

        // ---- P3: A m4,m5; stage B-line0(t+3) ----
        aa = *(const bf16x8*)&As[aoff + 4 * 512];
        ab = *(const bf16x8*)&As[aoff + 5 * 512];
        if (st) ST_B0(nb, t + 3);
        asm volatile("s_barrier" ::: "memory");
        asm volatile("s_waitcnt lgkmcnt(0)" ::: "memory");
        __builtin_amdgcn_sched_barrier(0);
        __builtin_amdgcn_s_setprio(1);
#pragma unroll
        for (int n = 0; n < 4; ++n) acc[4][n] = __builtin_amdgcn_mfma_f32_16x16x32_bf16(aa, bv[n], acc[4][n], 0, 0, 0);
#pragma unroll
        for (int n = 0; n < 4; ++n) acc[5][n] = __builtin_amdgcn_mfma_f32_16x16x32_bf16(ab, bv[n], acc[5][n], 0, 0, 0);
        __builtin_amdgcn_s_setprio(0);
        asm volatile("s_barrier" ::: "memory");

        // ---- P4: A m6,m7; stage B-line1(t+3); counted vmcnt; publish ----
        aa = *(const bf16x8*)&As[aoff + 6 * 512];
        ab = *(const bf16x8*)&As[aoff + 7 * 512];
        if (st) ST_B1(nb, t + 3);
        asm volatile("s_barrier" ::: "memory");
        asm volatile("s_waitcnt lgkmcnt(0)" ::: "memory");
        __builtin_amdgcn_sched_barrier(0);
        __builtin_amdgcn_s_setprio(1);
#pragma unroll
        for (int n = 0; n < 4; ++n) acc[6][n] = __builtin_amdgcn_mfma_f32_16x16x32_bf16(aa, bv[n], acc[6][n], 0, 0, 0);
#pragma unroll
        for (int n = 0; n < 4; ++n) acc[7][n] = __builtin_amdgcn_mfma_f32_16x16x32_bf16(ab, bv[n], acc[7][n], 0, 0, 0);
        __builtin_amdgcn_s_setprio(0);
        // Ledger (4 issues/tile): t<=14 in-flight t+1..t+3 (12) -> vmcnt(8)
        // leaves t+2,t+3; tile t+1 resident. t==15: 8 in flight -> vmcnt(4).
        // t==16: 4 -> vmcnt(0). t==17: none.
        if (t <= KT - 4)      asm volatile("s_waitcnt vmcnt(8)" ::: "memory");
        else if (t == KT - 3) asm volatile("s_waitcnt vmcnt(4)" ::: "memory");
        else if (t == KT - 2) asm volatile("s_waitcnt vmcnt(0)" ::: "memory");
        if (t < KT - 1) asm volatile("s_barrier" ::: "memory");
    }
#undef ST_A0
#undef ST_A1
#undef ST_B0
#undef ST_B1

    // ---- epilogue: plain stores (L2 write-combines the 64 B segments) ----
    const int crow0 = (int)mtile * BM + wr * 128 + ((lane >> 4) << 2);
    const int ccol0 = (int)ntile * BN + wc * 64 + (lane & 15);
#pragma unroll
    for (int m = 0; m < 8; ++m)
#pragma unroll
        for (int n = 0; n < 4; ++n) {
            float* cp = C + (size_t)(crow0 + m * 16) * NOUT + ccol0 + n * 16;
#pragma unroll
            for (int r = 0; r < 4; ++r) cp[(size_t)r * NOUT] = acc[m][n][r];
        }
}

// ---------- launcher ----------
extern "C" void kernel_launch(void* const* d_in, const int* in_sizes, int n_in,
                              void* d_out, int out_size, void* d_ws, size_t ws_size,
                              hipStream_t stream) {
    const float* x    = (const float*)d_in[0];
    const float* lnw  = (const float*)d_in[1];
    const float* lnb  = (const float*)d_in[2];
    const float* bw1  = (const float*)d_in[3];
    const float* sw1  = (const float*)d_in[4];
    const float* ss1  = (const float*)d_in[5];
    const float* bw2  = (const float*)d_in[6];
    const float* sw2  = (const float*)d_in[7];
    const float* ss2  = (const float*)d_in[8];

    char* ws = (char*)d_ws;
    uint16_t* w1L = (uint16_t*)ws;                          // 36,864 B
    uint16_t* w2p = (uint16_t*)(ws + 65536);                // 2,359,296 B
    uint16_t* a2  = (uint16_t*)(ws + 65536 + 2359296);      // 75,497,472 B
    float* out = (float*)d_out;

    pack_w1<<<dim3(72), dim3(256), 0, stream>>>(bw1, sw1, ss1, w1L);
    pack_w2<<<dim3((NOUT * K2 + 255) / 256), dim3(256), 0, stream>>>(bw2, sw2, ss2, w2p);
    featurize<<<dim3(BATCH / FBR), dim3(256), 0, stream>>>(x, lnw, lnb, w1L, a2);
    gemm2_kernel<<<dim3((BATCH / BM) * (NOUT / BN)), dim3(512), 0, stream>>>(a2, w2p, out);
}